// Round 3
// 276.138 us; speedup vs baseline: 1.0021x; 1.0021x over previous
//
#include <hip/hip_runtime.h>
#include <stdint.h>

#define THRESH 0.5f
#define VAR0 0.1f
#define VAR1 0.2f

typedef float f4u __attribute__((ext_vector_type(4), aligned(4)));

// ---------------------------------------------------------------------------
// Kernel A: fused match + main. r10 == r9 fused (kept for bisect):
//  - exp-sum folded into the prefetch: 1 live VGPR (s_pre) through matching
//    instead of 21. launch_bounds(256,8) caps VGPR at 64.
//  - siou pad 260: stage-1 bank index 4*n2+c (mod 32) -> exact 2-way (free).
// Arithmetic order is bit-identical to r8 (contract off, same exp sequence).
// ---------------------------------------------------------------------------
__global__ __launch_bounds__(256, 8) void fused_kernel(
    const float* __restrict__ loc_data, const float* __restrict__ conf_data,
    const float* __restrict__ priors, const float* __restrict__ tboxes,
    const int* __restrict__ labels,
    unsigned long long* __restrict__ part_best,   // [B][NBLK][NOBJ]
    float* __restrict__ loss_mine,
    float* __restrict__ ll_part, float* __restrict__ pc_part,
    int* __restrict__ np_part, unsigned int* __restrict__ done_ctr,
    int P, int C, int NOBJ, int NBLK)
{
#pragma clang fp contract(off)
    __shared__ float siou[16 * 260];          // [gt-in-chunk][slot], pad 260
    __shared__ float spv[32][17];             // stage-1 best value
    __shared__ unsigned char sps[32][20];     // stage-1 best slot
    __shared__ float ta[32];                  // per-GT area
    __shared__ float sll[4], spc[4];
    __shared__ int snp[4];

    const int b = blockIdx.y, bx = blockIdx.x, tid = threadIdx.x;
    const int p0 = bx * 256;
    const int p = p0 + tid;
    const int rows = min(256, P - p0);
    if (b == 0 && bx == 0 && tid == 0) *done_ctr = 0;   // reset for SelectCF

    const float4* tb = (const float4*)tboxes + (size_t)b * NOBJ;  // uniform

    // ---- conf prefetch: issue loads now, reduce to exp-sum after barrier ----
    const bool fastC = (C == 21);
    const float* row = conf_data + ((size_t)b * P + p) * C;
    const bool havefast = fastC && (tid < rows);
    f4u a0, a1, a2, a3, a4;
    float a5 = 0.f;
    if (havefast) {
        const f4u* r4 = (const f4u*)row;   // dword-aligned vector loads
        a0 = r4[0]; a1 = r4[1]; a2 = r4[2]; a3 = r4[3]; a4 = r4[4];
        a5 = row[20];
    }

    if (tid < NOBJ) {
        float4 t = tb[tid];
        ta[tid] = (t.z - t.x) * (t.w - t.y);
    }
    __syncthreads();

    // exp-sum NOW: frees the 20 conf regs before the matching phase.
    // Sequence (0..20 ascending) is bit-identical to r8 and to selectcf ph3.
    float s_pre = 0.f;
    if (havefast) {
        float s;
        s  = __expf(a0.x); s += __expf(a0.y); s += __expf(a0.z); s += __expf(a0.w);
        s += __expf(a1.x); s += __expf(a1.y); s += __expf(a1.z); s += __expf(a1.w);
        s += __expf(a2.x); s += __expf(a2.y); s += __expf(a2.z); s += __expf(a2.w);
        s += __expf(a3.x); s += __expf(a3.y); s += __expf(a3.z); s += __expf(a3.w);
        s += __expf(a4.x); s += __expf(a4.y); s += __expf(a4.z); s += __expf(a4.w);
        s += __expf(a5);
        s_pre = s;
    } else if (tid < rows) {
        float s = 0.f;
        for (int j = 0; j < C; ++j) s += __expf(row[j]);
        s_pre = s;
    }
    asm volatile("" : "+v"(s_pre));   // pin: don't let the exps sink back down

    const bool valid = (p < P);
    float ax = 0.f, ay = 0.f, bxx = 0.f, byy = 0.f, area_p = 0.f;
    if (valid) {
        float4 pr = ((const float4*)priors)[p];
        ax = pr.x - pr.z * 0.5f;
        ay = pr.y - pr.w * 0.5f;
        bxx = pr.x + pr.z * 0.5f;
        byy = pr.y + pr.w * 0.5f;
        area_p = (bxx - ax) * (byy - ay);
    }

    float bestv = -1.0f;
    int bestn = 0;
    for (int n0 = 0; n0 < NOBJ; n0 += 16) {
        const int jmax = min(16, NOBJ - n0);
#pragma unroll 4
        for (int j = 0; j < jmax; ++j) {
            float4 t = tb[n0 + j];            // uniform -> s_load_dwordx4
            float iou = -1.0f;
            if (valid) {
                float w = fminf(t.z, bxx) - fmaxf(t.x, ax); if (w < 0.f) w = 0.f;
                float h = fminf(t.w, byy) - fmaxf(t.y, ay); if (h < 0.f) h = 0.f;
                float inter = w * h;
                float denom = (ta[n0 + j] + area_p) - inter;
                iou = inter * __builtin_amdgcn_rcpf(denom);
                if (iou > bestv) { bestv = iou; bestn = n0 + j; }  // first-wins
            }
            siou[j * 260 + tid] = iou;
        }
        __syncthreads();
        // stage 1: thread (n2, c) reduces slots {c, 16+c, ..., 240+c}
        {
            const int n2 = tid & 15, c = tid >> 4;
            if (n2 < jmax) {
                float bv = -1.0f;
                int bs = 0;
                const int base = n2 * 260 + c;
                for (int j2 = 0; j2 < 16; ++j2) {
                    float v = siou[base + (j2 << 4)];
                    if (v > bv) { bv = v; bs = (j2 << 4) + c; }
                }
                spv[n0 + n2][c] = bv;
                sps[n0 + n2][c] = (unsigned char)bs;
            }
        }
        __syncthreads();
    }
    // stage 2: per-GT best over 16 chunks, (value, smallest-slot) lexicographic
    if (tid < NOBJ) {
        float bv = -1.0f;
        int bs = 0;
        for (int c2 = 0; c2 < 16; ++c2) {
            float v = spv[tid][c2];
            int s2 = (int)sps[tid][c2];
            if (v > bv || (v == bv && s2 < bs)) { bv = v; bs = s2; }
        }
        unsigned long long pk = 0ULL;
        if (bv >= 0.f) {
            unsigned int pp = (unsigned int)(p0 + bs);
            pk = (((unsigned long long)__float_as_uint(bv)) << 32) |
                 (unsigned long long)(0xFFFFFFFFu - pp);
        }
        part_best[((size_t)b * NBLK + bx) * NOBJ + tid] = pk;
    }

    // ---- CE from s_pre + smoothL1 on pre-fixup positives ----
    float ll = 0.f, pc = 0.f;
    int np = 0;
    if (tid < rows) {
        const size_t g = (size_t)b * P + p;
        int conf_t = (bestv < THRESH) ? 0 : labels[b * NOBJ + bestn] + 1;

        float ce = __logf(s_pre) - conf_data[g * (size_t)C + conf_t];

        bool pos = (conf_t > 0);
        loss_mine[g] = pos ? 0.f : ce;
        if (pos) {
            np = 1;
            pc = ce;
            float4 t = tb[bestn];             // divergent idx, L1-hot
            float4 pr = ((const float4*)priors)[p];
            float gcx = ((t.x + t.z) * 0.5f - pr.x) / (VAR0 * pr.z);
            float gcy = ((t.y + t.w) * 0.5f - pr.y) / (VAR0 * pr.w);
            float gw  = __logf((t.z - t.x) / pr.z) / VAR1;
            float gh  = __logf((t.w - t.y) / pr.w) / VAR1;
            float4 ld = ((const float4*)loc_data)[g];
            float d, a;
            d = ld.x - gcx; a = fabsf(d); ll += (a < 1.f) ? 0.5f * d * d : a - 0.5f;
            d = ld.y - gcy; a = fabsf(d); ll += (a < 1.f) ? 0.5f * d * d : a - 0.5f;
            d = ld.z - gw;  a = fabsf(d); ll += (a < 1.f) ? 0.5f * d * d : a - 0.5f;
            d = ld.w - gh;  a = fabsf(d); ll += (a < 1.f) ? 0.5f * d * d : a - 0.5f;
        }
    }

    for (int off = 32; off; off >>= 1) {
        ll += __shfl_down(ll, off, 64);
        pc += __shfl_down(pc, off, 64);
        np += __shfl_down(np, off, 64);
    }
    const int lane = tid & 63, wid = tid >> 6;
    if (lane == 0) { sll[wid] = ll; spc[wid] = pc; snp[wid] = np; }
    __syncthreads();
    if (tid == 0) {
        size_t slot = (size_t)b * NBLK + bx;
        ll_part[slot] = sll[0] + sll[1] + sll[2] + sll[3];
        pc_part[slot] = spc[0] + spc[1] + spc[2] + spc[3];
        np_part[slot] = snp[0] + snp[1] + snp[2] + snp[3];
    }
}

// ---------------------------------------------------------------------------
// SelectCF r10 == r8 VERBATIM (known-good, absmax 0.0 at 276.7 µs).
// The r9 12/12/8-bit rewrite produced NaN; reverted for bisect.
// ---------------------------------------------------------------------------
__global__ __launch_bounds__(1024) void selectcf_kernel(
    const float* __restrict__ loc_data, const float* __restrict__ conf_data,
    const float* __restrict__ priors, const float* __restrict__ tboxes,
    const int* __restrict__ labels,
    const unsigned long long* __restrict__ part_best,
    float* __restrict__ loss_mine,
    const float* __restrict__ ll_part, const float* __restrict__ pc_part,
    const int* __restrict__ np_part,
    double* __restrict__ neg, double* __restrict__ dll_b,
    double* __restrict__ dpc_b, int* __restrict__ npos_b,
    unsigned int* __restrict__ done_ctr, float* __restrict__ out,
    int P, int C, int NOBJ, int NBLK, int B, int ratio)
{
#pragma clang fp contract(off)
    const int b = blockIdx.x;
    const int tid = threadIdx.x;
    const int lane = tid & 63, wid = tid >> 6;   // 16 waves

    __shared__ float4 tr[32];
    __shared__ unsigned long long sp2[32][17];
    __shared__ unsigned long long bb[32];
    __shared__ int2 centry[32];
    __shared__ double sdll[32], sdpc[32];
    __shared__ int cnt_s, snp_s, snp_corr;
    __shared__ unsigned int hist[16][257];
    __shared__ unsigned int merged[256];
    __shared__ unsigned int sh_sel, sh_k;
    __shared__ double sd[16];
    __shared__ unsigned int sc[16];
    __shared__ double negv_s;
    __shared__ int is_last_s;

    if (tid == 0) { cnt_s = 0; snp_s = 0; snp_corr = 0; negv_s = 0.0; }
    if (tid < NOBJ) tr[tid] = ((const float4*)tboxes)[(size_t)b * NOBJ + tid];
    __syncthreads();

    if (tid < NBLK) atomicAdd(&snp_s, np_part[b * NBLK + tid]);

    // phase 1: reduce part_best over NBLK blocks (packed values unique/prior)
    {
        const int n = tid & 31, c = tid >> 5;
        if (tid < 512 && n < NOBJ) {
            unsigned long long best = 0ULL;
            for (int j = c; j < NBLK; j += 16) {
                unsigned long long v = part_best[((size_t)b * NBLK + j) * NOBJ + n];
                if (v > best) best = v;
            }
            sp2[n][c] = best;
        }
    }
    __syncthreads();
    if (tid < NOBJ) {
        unsigned long long best = 0ULL;
        for (int c = 0; c < 16; ++c) {
            unsigned long long v = sp2[tid][c];
            if (v > best) best = v;
        }
        bb[tid] = best;
    }
    __syncthreads();

    // phase 2: last-wins dedup, wave-0 shuffle version. Sequential semantics:
    // each distinct pidx maps to the LARGEST n that chose it. Lane n survives
    // iff no lane n' > n holds the same pidx. Entry order is irrelevant.
    if (wid == 0) {
        const bool have = (lane < NOBJ);
        unsigned int mypidx = have
            ? (0xFFFFFFFFu - (unsigned int)(bb[lane] & 0xFFFFFFFFu))
            : (0x80000000u + (unsigned int)lane);   // unique sentinel
        bool dead = false;
        for (int m = 0; m < NOBJ; ++m) {
            unsigned int o = __shfl(mypidx, m, 64);
            if (m > lane && o == mypidx) dead = true;
        }
        unsigned long long win = __ballot(have && !dead);
        if (have && !dead) {
            int rank = (int)__popcll(win & ((1ULL << lane) - 1ULL));
            centry[rank] = make_int2((int)mypidx, lane);
        }
        if (lane == 0) cnt_s = (int)__popcll(win);
    }
    __syncthreads();

    // phase 3: corrections for winner priors (arithmetic mirrors fused_kernel)
    if (tid < cnt_s) {
        const int pidx = centry[tid].x;
        const int n = centry[tid].y;
        float4 pr = ((const float4*)priors)[pidx];
        float ax = pr.x - pr.z * 0.5f;
        float ay = pr.y - pr.w * 0.5f;
        float bxx = pr.x + pr.z * 0.5f;
        float byy = pr.y + pr.w * 0.5f;
        float area_p = (bxx - ax) * (byy - ay);
        float bestv = -1.0f;
        int bestn = 0;
        for (int nn = 0; nn < NOBJ; ++nn) {
            float4 t = tr[nn];
            float w = fminf(t.z, bxx) - fmaxf(t.x, ax); if (w < 0.f) w = 0.f;
            float h = fminf(t.w, byy) - fmaxf(t.y, ay); if (h < 0.f) h = 0.f;
            float inter = w * h;
            float att = (t.z - t.x) * (t.w - t.y);   // same expr as fused ta[]
            float denom = (att + area_p) - inter;
            float iou = inter * __builtin_amdgcn_rcpf(denom);
            if (iou > bestv) { bestv = iou; bestn = nn; }
        }
        const float* row = conf_data + ((size_t)b * P + pidx) * C;
        float s = 0.f;
        for (int j = 0; j < C; ++j) s += __expf(row[j]);
        float lse = __logf(s);

        int old_conf = (bestv < THRESH) ? 0 : labels[b * NOBJ + bestn] + 1;
        int new_conf = labels[b * NOBJ + n] + 1;
        bool old_pos = (old_conf > 0);

        double dpc = old_pos ? ((double)row[old_conf] - (double)row[new_conf])
                             : (double)(lse - row[new_conf]);

        const size_t g = (size_t)b * P + pidx;
        float4 ld = ((const float4*)loc_data)[g];
        float sl1_new, sl1_old = 0.f;
        {
            float4 t = tr[n];
            float gcx = ((t.x + t.z) * 0.5f - pr.x) / (VAR0 * pr.z);
            float gcy = ((t.y + t.w) * 0.5f - pr.y) / (VAR0 * pr.w);
            float gw  = __logf((t.z - t.x) / pr.z) / VAR1;
            float gh  = __logf((t.w - t.y) / pr.w) / VAR1;
            float ll = 0.f, d, a;
            d = ld.x - gcx; a = fabsf(d); ll += (a < 1.f) ? 0.5f * d * d : a - 0.5f;
            d = ld.y - gcy; a = fabsf(d); ll += (a < 1.f) ? 0.5f * d * d : a - 0.5f;
            d = ld.z - gw;  a = fabsf(d); ll += (a < 1.f) ? 0.5f * d * d : a - 0.5f;
            d = ld.w - gh;  a = fabsf(d); ll += (a < 1.f) ? 0.5f * d * d : a - 0.5f;
            sl1_new = ll;
        }
        if (old_pos) {
            float4 t = tr[bestn];
            float gcx = ((t.x + t.z) * 0.5f - pr.x) / (VAR0 * pr.z);
            float gcy = ((t.y + t.w) * 0.5f - pr.y) / (VAR0 * pr.w);
            float gw  = __logf((t.z - t.x) / pr.z) / VAR1;
            float gh  = __logf((t.w - t.y) / pr.w) / VAR1;
            float ll = 0.f, d, a;
            d = ld.x - gcx; a = fabsf(d); ll += (a < 1.f) ? 0.5f * d * d : a - 0.5f;
            d = ld.y - gcy; a = fabsf(d); ll += (a < 1.f) ? 0.5f * d * d : a - 0.5f;
            d = ld.z - gw;  a = fabsf(d); ll += (a < 1.f) ? 0.5f * d * d : a - 0.5f;
            d = ld.w - gh;  a = fabsf(d); ll += (a < 1.f) ? 0.5f * d * d : a - 0.5f;
            sl1_old = ll;
        }
        sdll[tid] = (double)sl1_new - (double)sl1_old;
        sdpc[tid] = dpc;
        if (!old_pos) {
            atomicAdd(&snp_corr, 1);
            loss_mine[g] = 0.f;    // forced pos: excluded from mining
        }
    }
    __syncthreads();

    // phase 4: corrected k
    int k = ratio * (snp_s + snp_corr);
    if (k > P - 1) k = P - 1;

    // phase 5: radix select, re-reading loss_mine per round (L2/L3-hot,
    // float4 coalesced, no register array -> no spill)
    if (k > 0) {
        const f4u* fv4 = (const f4u*)(loss_mine + (size_t)b * P);
        const int P4 = P >> 2;                  // float4 count
        const int tail0 = P4 << 2;              // scalar tail start
        unsigned int prefix = 0, mask = 0;
        unsigned int kk = (unsigned int)k;
        for (int shift = 24; shift >= 0; shift -= 8) {
            for (int t = tid; t < 16 * 257; t += 1024) (&hist[0][0])[t] = 0;
            __syncthreads();
            unsigned int* h = hist[wid];
            for (int i4 = tid; i4 < P4; i4 += 1024) {
                f4u v4 = fv4[i4];
                unsigned int v;
                v = __float_as_uint(v4.x);
                if ((v & mask) == prefix) atomicAdd(&h[(v >> shift) & 255u], 1u);
                v = __float_as_uint(v4.y);
                if ((v & mask) == prefix) atomicAdd(&h[(v >> shift) & 255u], 1u);
                v = __float_as_uint(v4.z);
                if ((v & mask) == prefix) atomicAdd(&h[(v >> shift) & 255u], 1u);
                v = __float_as_uint(v4.w);
                if ((v & mask) == prefix) atomicAdd(&h[(v >> shift) & 255u], 1u);
            }
            for (int i = tail0 + tid; i < P; i += 1024) {
                unsigned int v = __float_as_uint(loss_mine[(size_t)b * P + i]);
                if ((v & mask) == prefix) atomicAdd(&h[(v >> shift) & 255u], 1u);
            }
            __syncthreads();
            if (tid < 256) {
                unsigned int s = 0;
                for (int w = 0; w < 16; ++w) s += hist[w][tid];
                merged[tid] = s;
            }
            __syncthreads();
            if (wid == 0) {
                unsigned int h0 = merged[4 * lane], h1 = merged[4 * lane + 1];
                unsigned int h2 = merged[4 * lane + 2], h3 = merged[4 * lane + 3];
                unsigned int s3 = h3, s2 = h2 + s3, s1 = h1 + s2, s0 = h0 + s1;
                unsigned int t = s0;
                unsigned int T = t;
                for (int off = 1; off < 64; off <<= 1) {
                    unsigned int o = __shfl_down(T, off, 64);
                    if (lane + off < 64) T += o;
                }
                unsigned int A = T - t;
                unsigned int S0 = A + s0, S1 = A + s1, S2 = A + s2, S3 = A + s3, S4 = A;
                if (S0 >= kk && S1 < kk) { sh_sel = 4 * lane + 0; sh_k = kk - S1; }
                if (S1 >= kk && S2 < kk) { sh_sel = 4 * lane + 1; sh_k = kk - S2; }
                if (S2 >= kk && S3 < kk) { sh_sel = 4 * lane + 2; sh_k = kk - S3; }
                if (S3 >= kk && S4 < kk) { sh_sel = 4 * lane + 3; sh_k = kk - S4; }
            }
            __syncthreads();
            prefix |= sh_sel << shift;
            mask |= 0xFFu << shift;
            kk = sh_k;
        }
        const float T = __uint_as_float(prefix);

        double sum = 0.0;
        unsigned int cnt = 0;
        for (int i4 = tid; i4 < P4; i4 += 1024) {
            f4u v4 = fv4[i4];
            if (v4.x > T) { sum += (double)v4.x; cnt++; }
            if (v4.y > T) { sum += (double)v4.y; cnt++; }
            if (v4.z > T) { sum += (double)v4.z; cnt++; }
            if (v4.w > T) { sum += (double)v4.w; cnt++; }
        }
        for (int i = tail0 + tid; i < P; i += 1024) {
            float v = loss_mine[(size_t)b * P + i];
            if (v > T) { sum += (double)v; cnt++; }
        }
        for (int off = 32; off; off >>= 1) {
            sum += __shfl_down(sum, off, 64);
            cnt += __shfl_down(cnt, off, 64);
        }
        if (lane == 0) { sd[wid] = sum; sc[wid] = cnt; }
        __syncthreads();
        if (tid == 0) {
            double S = 0.0;
            unsigned int Cn = 0;
            for (int w = 0; w < 16; ++w) { S += sd[w]; Cn += sc[w]; }
            negv_s = S + (double)((unsigned int)k - Cn) * (double)T;
        }
    }
    __syncthreads();

    // phase 6: publish per-batch results; last block finalizes
    if (tid == 0) {
        double DL = 0.0, DP = 0.0;
        for (int j = 0; j < cnt_s; ++j) { DL += sdll[j]; DP += sdpc[j]; }
        neg[b] = negv_s;
        dll_b[b] = DL;
        dpc_b[b] = DP;
        npos_b[b] = snp_s + snp_corr;
        __threadfence();
        unsigned int old = atomicAdd(done_ctr, 1u);
        is_last_s = (old == (unsigned int)B - 1) ? 1 : 0;
    }
    __syncthreads();
    if (!is_last_s) return;
    __threadfence();

    double LL = 0.0, PC = 0.0, NG = 0.0;
    long long NP = 0;
    const int NPART = B * NBLK;
    for (int i = tid; i < NPART; i += 1024) {
        LL += (double)ll_part[i];
        PC += (double)pc_part[i];
    }
    for (int i = tid; i < B; i += 1024) {
        NG += neg[i];
        LL += dll_b[i];
        PC += dpc_b[i];
        NP += (long long)npos_b[i];
    }
    for (int off = 32; off; off >>= 1) {
        LL += __shfl_down(LL, off, 64);
        PC += __shfl_down(PC, off, 64);
        NG += __shfl_down(NG, off, 64);
        NP += __shfl_down(NP, off, 64);
    }
    __shared__ double fll[16], fpc[16], fng[16];
    __shared__ long long fnp[16];
    if (lane == 0) { fll[wid] = LL; fpc[wid] = PC; fng[wid] = NG; fnp[wid] = NP; }
    __syncthreads();
    if (tid == 0) {
        double L = 0.0, Pc = 0.0, Ng = 0.0;
        long long Np = 0;
        for (int w = 0; w < 16; ++w) { L += fll[w]; Pc += fpc[w]; Ng += fng[w]; Np += fnp[w]; }
        if (Np < 1) Np = 1;
        double N = (double)Np;
        out[0] = (float)(L / N);
        out[1] = (float)((Pc + Ng) / N);
    }
}

extern "C" void kernel_launch(void* const* d_in, const int* in_sizes, int n_in,
                              void* d_out, int out_size, void* d_ws, size_t ws_size,
                              hipStream_t stream)
{
    const float* loc_data  = (const float*)d_in[0];
    const float* conf_data = (const float*)d_in[1];
    const float* priors    = (const float*)d_in[2];
    const float* tboxes    = (const float*)d_in[3];
    const int*   tlabels   = (const int*)d_in[4];

    const int P = in_sizes[2] / 4;
    const int B = (int)((long long)in_sizes[0] / ((long long)P * 4));
    const int C = (int)((long long)in_sizes[1] / ((long long)B * P));
    const int NOBJ = in_sizes[4] / B;
    const int NBLK = (P + 255) / 256;

    char* ws = (char*)d_ws;
    size_t off = 0;
    unsigned int* done_ctr = (unsigned int*)(ws + off);  off += 256;
    double* neg = (double*)(ws + off);                   off += (size_t)B * 8;
    off = (off + 255) & ~(size_t)255;
    double* dll_b = (double*)(ws + off);                 off += (size_t)B * 8;
    off = (off + 255) & ~(size_t)255;
    double* dpc_b = (double*)(ws + off);                 off += (size_t)B * 8;
    off = (off + 255) & ~(size_t)255;
    int* npos_b = (int*)(ws + off);                      off += (size_t)B * 4;
    off = (off + 255) & ~(size_t)255;
    float* ll_part = (float*)(ws + off);                 off += (size_t)B * NBLK * 4;
    off = (off + 255) & ~(size_t)255;
    float* pc_part = (float*)(ws + off);                 off += (size_t)B * NBLK * 4;
    off = (off + 255) & ~(size_t)255;
    int* np_part = (int*)(ws + off);                     off += (size_t)B * NBLK * 4;
    off = (off + 255) & ~(size_t)255;
    unsigned long long* part_best = (unsigned long long*)(ws + off);
    off += (size_t)B * NBLK * NOBJ * 8;
    off = (off + 255) & ~(size_t)255;
    float* loss_mine = (float*)(ws + off);

    dim3 grid(NBLK, B);
    fused_kernel<<<grid, 256, 0, stream>>>(
        loc_data, conf_data, priors, tboxes, tlabels,
        part_best, loss_mine, ll_part, pc_part, np_part, done_ctr,
        P, C, NOBJ, NBLK);
    selectcf_kernel<<<B, 1024, 0, stream>>>(
        loc_data, conf_data, priors, tboxes, tlabels,
        part_best, loss_mine, ll_part, pc_part, np_part,
        neg, dll_b, dpc_b, npos_b, done_ctr, (float*)d_out,
        P, C, NOBJ, NBLK, B, 3);
}

// Round 4
// 275.597 us; speedup vs baseline: 1.0041x; 1.0020x over previous
//
#include <hip/hip_runtime.h>
#include <stdint.h>

#define THRESH 0.5f
#define VAR0 0.1f
#define VAR1 0.2f
#define CAP 6144

typedef float f4u __attribute__((ext_vector_type(4), aligned(4)));

// ---------------------------------------------------------------------------
// Kernel A: fused match + main (passing r10 version, unchanged):
//  - exp-sum folded into the prefetch: 1 live VGPR (s_pre) through matching.
//  - siou pad 260: stage-1 bank index 4*n2+c (mod 32) -> exact 2-way (free).
// ---------------------------------------------------------------------------
__global__ __launch_bounds__(256, 8) void fused_kernel(
    const float* __restrict__ loc_data, const float* __restrict__ conf_data,
    const float* __restrict__ priors, const float* __restrict__ tboxes,
    const int* __restrict__ labels,
    unsigned long long* __restrict__ part_best,   // [B][NBLK][NOBJ]
    float* __restrict__ loss_mine,
    float* __restrict__ ll_part, float* __restrict__ pc_part,
    int* __restrict__ np_part, unsigned int* __restrict__ done_ctr,
    int P, int C, int NOBJ, int NBLK)
{
#pragma clang fp contract(off)
    __shared__ float siou[16 * 260];          // [gt-in-chunk][slot], pad 260
    __shared__ float spv[32][17];             // stage-1 best value
    __shared__ unsigned char sps[32][20];     // stage-1 best slot
    __shared__ float ta[32];                  // per-GT area
    __shared__ float sll[4], spc[4];
    __shared__ int snp[4];

    const int b = blockIdx.y, bx = blockIdx.x, tid = threadIdx.x;
    const int p0 = bx * 256;
    const int p = p0 + tid;
    const int rows = min(256, P - p0);
    if (b == 0 && bx == 0 && tid == 0) *done_ctr = 0;   // reset for SelectCF

    const float4* tb = (const float4*)tboxes + (size_t)b * NOBJ;  // uniform

    // ---- conf prefetch: issue loads now, reduce to exp-sum after barrier ----
    const bool fastC = (C == 21);
    const float* row = conf_data + ((size_t)b * P + p) * C;
    const bool havefast = fastC && (tid < rows);
    f4u a0, a1, a2, a3, a4;
    float a5 = 0.f;
    if (havefast) {
        const f4u* r4 = (const f4u*)row;   // dword-aligned vector loads
        a0 = r4[0]; a1 = r4[1]; a2 = r4[2]; a3 = r4[3]; a4 = r4[4];
        a5 = row[20];
    }

    if (tid < NOBJ) {
        float4 t = tb[tid];
        ta[tid] = (t.z - t.x) * (t.w - t.y);
    }
    __syncthreads();

    // exp-sum NOW: frees the 20 conf regs before the matching phase.
    float s_pre = 0.f;
    if (havefast) {
        float s;
        s  = __expf(a0.x); s += __expf(a0.y); s += __expf(a0.z); s += __expf(a0.w);
        s += __expf(a1.x); s += __expf(a1.y); s += __expf(a1.z); s += __expf(a1.w);
        s += __expf(a2.x); s += __expf(a2.y); s += __expf(a2.z); s += __expf(a2.w);
        s += __expf(a3.x); s += __expf(a3.y); s += __expf(a3.z); s += __expf(a3.w);
        s += __expf(a4.x); s += __expf(a4.y); s += __expf(a4.z); s += __expf(a4.w);
        s += __expf(a5);
        s_pre = s;
    } else if (tid < rows) {
        float s = 0.f;
        for (int j = 0; j < C; ++j) s += __expf(row[j]);
        s_pre = s;
    }
    asm volatile("" : "+v"(s_pre));   // pin: don't let the exps sink back down

    const bool valid = (p < P);
    float ax = 0.f, ay = 0.f, bxx = 0.f, byy = 0.f, area_p = 0.f;
    if (valid) {
        float4 pr = ((const float4*)priors)[p];
        ax = pr.x - pr.z * 0.5f;
        ay = pr.y - pr.w * 0.5f;
        bxx = pr.x + pr.z * 0.5f;
        byy = pr.y + pr.w * 0.5f;
        area_p = (bxx - ax) * (byy - ay);
    }

    float bestv = -1.0f;
    int bestn = 0;
    for (int n0 = 0; n0 < NOBJ; n0 += 16) {
        const int jmax = min(16, NOBJ - n0);
#pragma unroll 4
        for (int j = 0; j < jmax; ++j) {
            float4 t = tb[n0 + j];            // uniform -> s_load_dwordx4
            float iou = -1.0f;
            if (valid) {
                float w = fminf(t.z, bxx) - fmaxf(t.x, ax); if (w < 0.f) w = 0.f;
                float h = fminf(t.w, byy) - fmaxf(t.y, ay); if (h < 0.f) h = 0.f;
                float inter = w * h;
                float denom = (ta[n0 + j] + area_p) - inter;
                iou = inter * __builtin_amdgcn_rcpf(denom);
                if (iou > bestv) { bestv = iou; bestn = n0 + j; }  // first-wins
            }
            siou[j * 260 + tid] = iou;
        }
        __syncthreads();
        // stage 1: thread (n2, c) reduces slots {c, 16+c, ..., 240+c}
        {
            const int n2 = tid & 15, c = tid >> 4;
            if (n2 < jmax) {
                float bv = -1.0f;
                int bs = 0;
                const int base = n2 * 260 + c;
                for (int j2 = 0; j2 < 16; ++j2) {
                    float v = siou[base + (j2 << 4)];
                    if (v > bv) { bv = v; bs = (j2 << 4) + c; }
                }
                spv[n0 + n2][c] = bv;
                sps[n0 + n2][c] = (unsigned char)bs;
            }
        }
        __syncthreads();
    }
    // stage 2: per-GT best over 16 chunks, (value, smallest-slot) lexicographic
    if (tid < NOBJ) {
        float bv = -1.0f;
        int bs = 0;
        for (int c2 = 0; c2 < 16; ++c2) {
            float v = spv[tid][c2];
            int s2 = (int)sps[tid][c2];
            if (v > bv || (v == bv && s2 < bs)) { bv = v; bs = s2; }
        }
        unsigned long long pk = 0ULL;
        if (bv >= 0.f) {
            unsigned int pp = (unsigned int)(p0 + bs);
            pk = (((unsigned long long)__float_as_uint(bv)) << 32) |
                 (unsigned long long)(0xFFFFFFFFu - pp);
        }
        part_best[((size_t)b * NBLK + bx) * NOBJ + tid] = pk;
    }

    // ---- CE from s_pre + smoothL1 on pre-fixup positives ----
    float ll = 0.f, pc = 0.f;
    int np = 0;
    if (tid < rows) {
        const size_t g = (size_t)b * P + p;
        int conf_t = (bestv < THRESH) ? 0 : labels[b * NOBJ + bestn] + 1;

        float ce = __logf(s_pre) - conf_data[g * (size_t)C + conf_t];

        bool pos = (conf_t > 0);
        loss_mine[g] = pos ? 0.f : ce;
        if (pos) {
            np = 1;
            pc = ce;
            float4 t = tb[bestn];             // divergent idx, L1-hot
            float4 pr = ((const float4*)priors)[p];
            float gcx = ((t.x + t.z) * 0.5f - pr.x) / (VAR0 * pr.z);
            float gcy = ((t.y + t.w) * 0.5f - pr.y) / (VAR0 * pr.w);
            float gw  = __logf((t.z - t.x) / pr.z) / VAR1;
            float gh  = __logf((t.w - t.y) / pr.w) / VAR1;
            float4 ld = ((const float4*)loc_data)[g];
            float d, a;
            d = ld.x - gcx; a = fabsf(d); ll += (a < 1.f) ? 0.5f * d * d : a - 0.5f;
            d = ld.y - gcy; a = fabsf(d); ll += (a < 1.f) ? 0.5f * d * d : a - 0.5f;
            d = ld.z - gw;  a = fabsf(d); ll += (a < 1.f) ? 0.5f * d * d : a - 0.5f;
            d = ld.w - gh;  a = fabsf(d); ll += (a < 1.f) ? 0.5f * d * d : a - 0.5f;
        }
    }

    for (int off = 32; off; off >>= 1) {
        ll += __shfl_down(ll, off, 64);
        pc += __shfl_down(pc, off, 64);
        np += __shfl_down(np, off, 64);
    }
    const int lane = tid & 63, wid = tid >> 6;
    if (lane == 0) { sll[wid] = ll; spc[wid] = pc; snp[wid] = np; }
    __syncthreads();
    if (tid == 0) {
        size_t slot = (size_t)b * NBLK + bx;
        ll_part[slot] = sll[0] + sll[1] + sll[2] + sll[3];
        pc_part[slot] = spc[0] + spc[1] + spc[2] + spc[3];
        np_part[slot] = snp[0] + snp[1] + snp[2] + snp[3];
    }
}

// ---------------------------------------------------------------------------
// SelectCF r11: r8's proven phase structure; phase 5 keeps the SAME per-wave
// hist + merged + wave-0 scan for all 4 rounds, but after the shift==16 round
// a compact pass moves the 16-bit-prefix-matching candidates into LDS (cbuf)
// and pre-sums values strictly above the prefix class (provably in top-k).
// Rounds shift 8/0 and the final sum then read cbuf instead of global.
// Global loss_mine passes: 5 -> 3. Fallback to r8's global paths if
// ncand > CAP. Race discipline: ccnt/cbuf writes only after the end-of-round
// barrier (sh_sel/sh_k reads complete), reads after a further barrier.
// ---------------------------------------------------------------------------
__global__ __launch_bounds__(1024) void selectcf_kernel(
    const float* __restrict__ loc_data, const float* __restrict__ conf_data,
    const float* __restrict__ priors, const float* __restrict__ tboxes,
    const int* __restrict__ labels,
    const unsigned long long* __restrict__ part_best,
    float* __restrict__ loss_mine,
    const float* __restrict__ ll_part, const float* __restrict__ pc_part,
    const int* __restrict__ np_part,
    double* __restrict__ neg, double* __restrict__ dll_b,
    double* __restrict__ dpc_b, int* __restrict__ npos_b,
    unsigned int* __restrict__ done_ctr, float* __restrict__ out,
    int P, int C, int NOBJ, int NBLK, int B, int ratio)
{
#pragma clang fp contract(off)
    const int b = blockIdx.x;
    const int tid = threadIdx.x;
    const int lane = tid & 63, wid = tid >> 6;   // 16 waves

    __shared__ float4 tr[32];
    __shared__ unsigned long long sp2[32][17];
    __shared__ unsigned long long bb[32];
    __shared__ int2 centry[32];
    __shared__ double sdll[32], sdpc[32];
    __shared__ int cnt_s, snp_s, snp_corr;
    __shared__ unsigned int hist[16][257];
    __shared__ unsigned int merged[256];
    __shared__ unsigned int sh_sel, sh_k;
    __shared__ float cbuf[CAP];
    __shared__ int ccnt;
    __shared__ double sd[16];
    __shared__ unsigned int sc[16];
    __shared__ double negv_s;
    __shared__ int is_last_s;

    if (tid == 0) { cnt_s = 0; snp_s = 0; snp_corr = 0; negv_s = 0.0; }
    if (tid < NOBJ) tr[tid] = ((const float4*)tboxes)[(size_t)b * NOBJ + tid];
    __syncthreads();

    if (tid < NBLK) atomicAdd(&snp_s, np_part[b * NBLK + tid]);

    // phase 1: reduce part_best over NBLK blocks (packed values unique/prior)
    {
        const int n = tid & 31, c = tid >> 5;
        if (tid < 512 && n < NOBJ) {
            unsigned long long best = 0ULL;
            for (int j = c; j < NBLK; j += 16) {
                unsigned long long v = part_best[((size_t)b * NBLK + j) * NOBJ + n];
                if (v > best) best = v;
            }
            sp2[n][c] = best;
        }
    }
    __syncthreads();
    if (tid < NOBJ) {
        unsigned long long best = 0ULL;
        for (int c = 0; c < 16; ++c) {
            unsigned long long v = sp2[tid][c];
            if (v > best) best = v;
        }
        bb[tid] = best;
    }
    __syncthreads();

    // phase 2: last-wins dedup, wave-0 shuffle version
    if (wid == 0) {
        const bool have = (lane < NOBJ);
        unsigned int mypidx = have
            ? (0xFFFFFFFFu - (unsigned int)(bb[lane] & 0xFFFFFFFFu))
            : (0x80000000u + (unsigned int)lane);   // unique sentinel
        bool dead = false;
        for (int m = 0; m < NOBJ; ++m) {
            unsigned int o = __shfl(mypidx, m, 64);
            if (m > lane && o == mypidx) dead = true;
        }
        unsigned long long win = __ballot(have && !dead);
        if (have && !dead) {
            int rank = (int)__popcll(win & ((1ULL << lane) - 1ULL));
            centry[rank] = make_int2((int)mypidx, lane);
        }
        if (lane == 0) cnt_s = (int)__popcll(win);
    }
    __syncthreads();

    // phase 3: corrections for winner priors (arithmetic mirrors fused_kernel)
    if (tid < cnt_s) {
        const int pidx = centry[tid].x;
        const int n = centry[tid].y;
        float4 pr = ((const float4*)priors)[pidx];
        float ax = pr.x - pr.z * 0.5f;
        float ay = pr.y - pr.w * 0.5f;
        float bxx = pr.x + pr.z * 0.5f;
        float byy = pr.y + pr.w * 0.5f;
        float area_p = (bxx - ax) * (byy - ay);
        float bestv = -1.0f;
        int bestn = 0;
        for (int nn = 0; nn < NOBJ; ++nn) {
            float4 t = tr[nn];
            float w = fminf(t.z, bxx) - fmaxf(t.x, ax); if (w < 0.f) w = 0.f;
            float h = fminf(t.w, byy) - fmaxf(t.y, ay); if (h < 0.f) h = 0.f;
            float inter = w * h;
            float att = (t.z - t.x) * (t.w - t.y);   // same expr as fused ta[]
            float denom = (att + area_p) - inter;
            float iou = inter * __builtin_amdgcn_rcpf(denom);
            if (iou > bestv) { bestv = iou; bestn = nn; }
        }
        const float* row = conf_data + ((size_t)b * P + pidx) * C;
        float s = 0.f;
        for (int j = 0; j < C; ++j) s += __expf(row[j]);
        float lse = __logf(s);

        int old_conf = (bestv < THRESH) ? 0 : labels[b * NOBJ + bestn] + 1;
        int new_conf = labels[b * NOBJ + n] + 1;
        bool old_pos = (old_conf > 0);

        double dpc = old_pos ? ((double)row[old_conf] - (double)row[new_conf])
                             : (double)(lse - row[new_conf]);

        const size_t g = (size_t)b * P + pidx;
        float4 ld = ((const float4*)loc_data)[g];
        float sl1_new, sl1_old = 0.f;
        {
            float4 t = tr[n];
            float gcx = ((t.x + t.z) * 0.5f - pr.x) / (VAR0 * pr.z);
            float gcy = ((t.y + t.w) * 0.5f - pr.y) / (VAR0 * pr.w);
            float gw  = __logf((t.z - t.x) / pr.z) / VAR1;
            float gh  = __logf((t.w - t.y) / pr.w) / VAR1;
            float ll = 0.f, d, a;
            d = ld.x - gcx; a = fabsf(d); ll += (a < 1.f) ? 0.5f * d * d : a - 0.5f;
            d = ld.y - gcy; a = fabsf(d); ll += (a < 1.f) ? 0.5f * d * d : a - 0.5f;
            d = ld.z - gw;  a = fabsf(d); ll += (a < 1.f) ? 0.5f * d * d : a - 0.5f;
            d = ld.w - gh;  a = fabsf(d); ll += (a < 1.f) ? 0.5f * d * d : a - 0.5f;
            sl1_new = ll;
        }
        if (old_pos) {
            float4 t = tr[bestn];
            float gcx = ((t.x + t.z) * 0.5f - pr.x) / (VAR0 * pr.z);
            float gcy = ((t.y + t.w) * 0.5f - pr.y) / (VAR0 * pr.w);
            float gw  = __logf((t.z - t.x) / pr.z) / VAR1;
            float gh  = __logf((t.w - t.y) / pr.w) / VAR1;
            float ll = 0.f, d, a;
            d = ld.x - gcx; a = fabsf(d); ll += (a < 1.f) ? 0.5f * d * d : a - 0.5f;
            d = ld.y - gcy; a = fabsf(d); ll += (a < 1.f) ? 0.5f * d * d : a - 0.5f;
            d = ld.z - gw;  a = fabsf(d); ll += (a < 1.f) ? 0.5f * d * d : a - 0.5f;
            d = ld.w - gh;  a = fabsf(d); ll += (a < 1.f) ? 0.5f * d * d : a - 0.5f;
            sl1_old = ll;
        }
        sdll[tid] = (double)sl1_new - (double)sl1_old;
        sdpc[tid] = dpc;
        if (!old_pos) {
            atomicAdd(&snp_corr, 1);
            loss_mine[g] = 0.f;    // forced pos: excluded from mining
        }
    }
    __syncthreads();

    // phase 4: corrected k
    int k = ratio * (snp_s + snp_corr);
    if (k > P - 1) k = P - 1;

    // phase 5: radix select (r8 machinery) + post-round-16 LDS compaction
    if (k > 0) {
        const f4u* fv4 = (const f4u*)(loss_mine + (size_t)b * P);
        const int P4 = P >> 2;                  // float4 count
        const int tail0 = P4 << 2;              // scalar tail start
        unsigned int prefix = 0, mask = 0;
        unsigned int kk = (unsigned int)k;
        int ncand = -1;                         // <0: compact not yet done
        double psum = 0.0;                      // sum of values above prefix16
        unsigned int pcnt = 0;

        for (int shift = 24; shift >= 0; shift -= 8) {
            for (int t = tid; t < 16 * 257; t += 1024) (&hist[0][0])[t] = 0;
            __syncthreads();
            unsigned int* h = hist[wid];
            const bool lds_src = (ncand >= 0) && (ncand <= CAP);
            if (lds_src) {
                // candidates all match prefix16; predicate filters bits 15:8
                // once those are fixed (shift==0 round).
                for (int i = tid; i < ncand; i += 1024) {
                    unsigned int v = __float_as_uint(cbuf[i]);
                    if ((v & mask) == prefix) atomicAdd(&h[(v >> shift) & 255u], 1u);
                }
            } else {
                for (int i4 = tid; i4 < P4; i4 += 1024) {
                    f4u v4 = fv4[i4];
                    unsigned int v;
                    v = __float_as_uint(v4.x);
                    if ((v & mask) == prefix) atomicAdd(&h[(v >> shift) & 255u], 1u);
                    v = __float_as_uint(v4.y);
                    if ((v & mask) == prefix) atomicAdd(&h[(v >> shift) & 255u], 1u);
                    v = __float_as_uint(v4.z);
                    if ((v & mask) == prefix) atomicAdd(&h[(v >> shift) & 255u], 1u);
                    v = __float_as_uint(v4.w);
                    if ((v & mask) == prefix) atomicAdd(&h[(v >> shift) & 255u], 1u);
                }
                for (int i = tail0 + tid; i < P; i += 1024) {
                    unsigned int v = __float_as_uint(loss_mine[(size_t)b * P + i]);
                    if ((v & mask) == prefix) atomicAdd(&h[(v >> shift) & 255u], 1u);
                }
            }
            __syncthreads();
            if (tid < 256) {
                unsigned int s = 0;
                for (int w = 0; w < 16; ++w) s += hist[w][tid];
                merged[tid] = s;
            }
            __syncthreads();
            if (wid == 0) {
                unsigned int h0 = merged[4 * lane], h1 = merged[4 * lane + 1];
                unsigned int h2 = merged[4 * lane + 2], h3 = merged[4 * lane + 3];
                unsigned int s3 = h3, s2 = h2 + s3, s1 = h1 + s2, s0 = h0 + s1;
                unsigned int t = s0;
                unsigned int T = t;
                for (int off = 1; off < 64; off <<= 1) {
                    unsigned int o = __shfl_down(T, off, 64);
                    if (lane + off < 64) T += o;
                }
                unsigned int A = T - t;
                unsigned int S0 = A + s0, S1 = A + s1, S2 = A + s2, S3 = A + s3, S4 = A;
                if (S0 >= kk && S1 < kk) { sh_sel = 4 * lane + 0; sh_k = kk - S1; }
                if (S1 >= kk && S2 < kk) { sh_sel = 4 * lane + 1; sh_k = kk - S2; }
                if (S2 >= kk && S3 < kk) { sh_sel = 4 * lane + 2; sh_k = kk - S3; }
                if (S3 >= kk && S4 < kk) { sh_sel = 4 * lane + 3; sh_k = kk - S4; }
            }
            __syncthreads();
            prefix |= sh_sel << shift;
            mask |= 0xFFu << shift;
            kk = sh_k;

            if (shift == 16) {
                // compact pass: prefix now covers bits 31:16.
                // pf >  prefix -> definitely in top-k: accumulate now.
                // pf == prefix -> candidate: stash in LDS.
                // pf <  prefix -> below threshold class: drop.
                if (tid == 0) ccnt = 0;    // sh_sel/sh_k reads already done above
                __syncthreads();
                for (int i4 = tid; i4 < P4; i4 += 1024) {
                    f4u v4 = fv4[i4];
                    unsigned int v, pf;
                    v = __float_as_uint(v4.x); pf = v & 0xFFFF0000u;
                    if (pf == prefix) { int s_ = atomicAdd(&ccnt, 1); if (s_ < CAP) cbuf[s_] = v4.x; }
                    else if (pf > prefix) { psum += (double)v4.x; pcnt++; }
                    v = __float_as_uint(v4.y); pf = v & 0xFFFF0000u;
                    if (pf == prefix) { int s_ = atomicAdd(&ccnt, 1); if (s_ < CAP) cbuf[s_] = v4.y; }
                    else if (pf > prefix) { psum += (double)v4.y; pcnt++; }
                    v = __float_as_uint(v4.z); pf = v & 0xFFFF0000u;
                    if (pf == prefix) { int s_ = atomicAdd(&ccnt, 1); if (s_ < CAP) cbuf[s_] = v4.z; }
                    else if (pf > prefix) { psum += (double)v4.z; pcnt++; }
                    v = __float_as_uint(v4.w); pf = v & 0xFFFF0000u;
                    if (pf == prefix) { int s_ = atomicAdd(&ccnt, 1); if (s_ < CAP) cbuf[s_] = v4.w; }
                    else if (pf > prefix) { psum += (double)v4.w; pcnt++; }
                }
                for (int i = tail0 + tid; i < P; i += 1024) {
                    float fvv = loss_mine[(size_t)b * P + i];
                    unsigned int v = __float_as_uint(fvv);
                    unsigned int pf = v & 0xFFFF0000u;
                    if (pf == prefix) { int s_ = atomicAdd(&ccnt, 1); if (s_ < CAP) cbuf[s_] = fvv; }
                    else if (pf > prefix) { psum += (double)fvv; pcnt++; }
                }
                __syncthreads();
                ncand = ccnt;              // uniform read after barrier
            }
        }
        const float T = __uint_as_float(prefix);

        double sum;
        unsigned int cnt;
        if (ncand >= 0 && ncand <= CAP) {
            // values above prefix16 pre-summed; finish from LDS candidates
            sum = psum; cnt = pcnt;
            for (int i = tid; i < ncand; i += 1024) {
                float v = cbuf[i];
                if (v > T) { sum += (double)v; cnt++; }
            }
        } else {
            // overflow fallback: full global pass (r8 path)
            sum = 0.0; cnt = 0;
            for (int i4 = tid; i4 < P4; i4 += 1024) {
                f4u v4 = fv4[i4];
                if (v4.x > T) { sum += (double)v4.x; cnt++; }
                if (v4.y > T) { sum += (double)v4.y; cnt++; }
                if (v4.z > T) { sum += (double)v4.z; cnt++; }
                if (v4.w > T) { sum += (double)v4.w; cnt++; }
            }
            for (int i = tail0 + tid; i < P; i += 1024) {
                float v = loss_mine[(size_t)b * P + i];
                if (v > T) { sum += (double)v; cnt++; }
            }
        }
        for (int off = 32; off; off >>= 1) {
            sum += __shfl_down(sum, off, 64);
            cnt += __shfl_down(cnt, off, 64);
        }
        if (lane == 0) { sd[wid] = sum; sc[wid] = cnt; }
        __syncthreads();
        if (tid == 0) {
            double S = 0.0;
            unsigned int Cn = 0;
            for (int w = 0; w < 16; ++w) { S += sd[w]; Cn += sc[w]; }
            negv_s = S + (double)((unsigned int)k - Cn) * (double)T;
        }
    }
    __syncthreads();

    // phase 6: publish per-batch results; last block finalizes
    if (tid == 0) {
        double DL = 0.0, DP = 0.0;
        for (int j = 0; j < cnt_s; ++j) { DL += sdll[j]; DP += sdpc[j]; }
        neg[b] = negv_s;
        dll_b[b] = DL;
        dpc_b[b] = DP;
        npos_b[b] = snp_s + snp_corr;
        __threadfence();
        unsigned int old = atomicAdd(done_ctr, 1u);
        is_last_s = (old == (unsigned int)B - 1) ? 1 : 0;
    }
    __syncthreads();
    if (!is_last_s) return;
    __threadfence();

    double LL = 0.0, PC = 0.0, NG = 0.0;
    long long NP = 0;
    const int NPART = B * NBLK;
    for (int i = tid; i < NPART; i += 1024) {
        LL += (double)ll_part[i];
        PC += (double)pc_part[i];
    }
    for (int i = tid; i < B; i += 1024) {
        NG += neg[i];
        LL += dll_b[i];
        PC += dpc_b[i];
        NP += (long long)npos_b[i];
    }
    for (int off = 32; off; off >>= 1) {
        LL += __shfl_down(LL, off, 64);
        PC += __shfl_down(PC, off, 64);
        NG += __shfl_down(NG, off, 64);
        NP += __shfl_down(NP, off, 64);
    }
    __shared__ double fll[16], fpc[16], fng[16];
    __shared__ long long fnp[16];
    if (lane == 0) { fll[wid] = LL; fpc[wid] = PC; fng[wid] = NG; fnp[wid] = NP; }
    __syncthreads();
    if (tid == 0) {
        double L = 0.0, Pc = 0.0, Ng = 0.0;
        long long Np = 0;
        for (int w = 0; w < 16; ++w) { L += fll[w]; Pc += fpc[w]; Ng += fng[w]; Np += fnp[w]; }
        if (Np < 1) Np = 1;
        double N = (double)Np;
        out[0] = (float)(L / N);
        out[1] = (float)((Pc + Ng) / N);
    }
}

extern "C" void kernel_launch(void* const* d_in, const int* in_sizes, int n_in,
                              void* d_out, int out_size, void* d_ws, size_t ws_size,
                              hipStream_t stream)
{
    const float* loc_data  = (const float*)d_in[0];
    const float* conf_data = (const float*)d_in[1];
    const float* priors    = (const float*)d_in[2];
    const float* tboxes    = (const float*)d_in[3];
    const int*   tlabels   = (const int*)d_in[4];

    const int P = in_sizes[2] / 4;
    const int B = (int)((long long)in_sizes[0] / ((long long)P * 4));
    const int C = (int)((long long)in_sizes[1] / ((long long)B * P));
    const int NOBJ = in_sizes[4] / B;
    const int NBLK = (P + 255) / 256;

    char* ws = (char*)d_ws;
    size_t off = 0;
    unsigned int* done_ctr = (unsigned int*)(ws + off);  off += 256;
    double* neg = (double*)(ws + off);                   off += (size_t)B * 8;
    off = (off + 255) & ~(size_t)255;
    double* dll_b = (double*)(ws + off);                 off += (size_t)B * 8;
    off = (off + 255) & ~(size_t)255;
    double* dpc_b = (double*)(ws + off);                 off += (size_t)B * 8;
    off = (off + 255) & ~(size_t)255;
    int* npos_b = (int*)(ws + off);                      off += (size_t)B * 4;
    off = (off + 255) & ~(size_t)255;
    float* ll_part = (float*)(ws + off);                 off += (size_t)B * NBLK * 4;
    off = (off + 255) & ~(size_t)255;
    float* pc_part = (float*)(ws + off);                 off += (size_t)B * NBLK * 4;
    off = (off + 255) & ~(size_t)255;
    int* np_part = (int*)(ws + off);                     off += (size_t)B * NBLK * 4;
    off = (off + 255) & ~(size_t)255;
    unsigned long long* part_best = (unsigned long long*)(ws + off);
    off += (size_t)B * NBLK * NOBJ * 8;
    off = (off + 255) & ~(size_t)255;
    float* loss_mine = (float*)(ws + off);

    dim3 grid(NBLK, B);
    fused_kernel<<<grid, 256, 0, stream>>>(
        loc_data, conf_data, priors, tboxes, tlabels,
        part_best, loss_mine, ll_part, pc_part, np_part, done_ctr,
        P, C, NOBJ, NBLK);
    selectcf_kernel<<<B, 1024, 0, stream>>>(
        loc_data, conf_data, priors, tboxes, tlabels,
        part_best, loss_mine, ll_part, pc_part, np_part,
        neg, dll_b, dpc_b, npos_b, done_ctr, (float*)d_out,
        P, C, NOBJ, NBLK, B, 3);
}